// Round 3
// baseline (1752.636 us; speedup 1.0000x reference)
//
#include <hip/hip_runtime.h>

// EdgeFeatGAE: 2-layer GCN (R=4 relations share x, W1, W2), out = sum over
// embed dim -> [R, N].
// Algebra: layer2 collapses to scalar per node (wrow[j] = sum_k W2[j][k]);
// H0 = x@W1 is relation-independent.
// R3: radix-partition edges into 512-node dst-buckets (LDS-staged, coalesced
// writes — kills R2 k_scatter's 16x write amplification), then per-bucket
// LDS-accumulator aggregation (zero global atomics anywhere).

constexpr int N    = 100000;
constexpr int E    = 1600000;
constexpr int R    = 4;
constexpr int FEAT = 128;
constexpr int HID  = 32;
constexpr int EMB  = 16;
constexpr int M    = R * N;
constexpr int BS   = 256;
constexpr int SH    = 9;                          // bucket = dst >> 9
constexpr int BSPAN = 1 << SH;                    // 512 nodes per bucket
constexpr int NBUCK = (N + BSPAN - 1) / BSPAN;    // 196 buckets per relation
constexpr int CH    = 8192;                       // edges per partition block
constexpr int NBKr  = (E + CH - 1) / CH;          // 196 blocks per relation
constexpr int RB    = R * NBUCK;                  // 784 buckets total
constexpr int NT    = RB * NBKr;                  // 153664 table entries
constexpr int TOTE  = R * E;                      // 6.4M records

// ---------------- H0 = x @ W1  [N,32] ----------------
__global__ void k_gemm_h0(const float* __restrict__ x, const float* __restrict__ W1,
                          float* __restrict__ H0) {
    int t = blockIdx.x * blockDim.x + threadIdx.x;
    if (t >= N * HID) return;
    int j = t & (HID - 1);
    int i = t >> 5;
    const float* xr = x + (size_t)i * FEAT;
    float acc = 0.f;
#pragma unroll 8
    for (int k = 0; k < FEAT; ++k)
        acc = fmaf(xr[k], W1[k * HID + j], acc);
    H0[t] = acc;
}

// ---------------- per-(bucket, block) histogram ----------------
__global__ void k_hist(const int* __restrict__ eis, int* __restrict__ T) {
    __shared__ int hist[NBUCK];
    int r = blockIdx.x / NBKr, k = blockIdx.x - r * NBKr;
    const int* dstp = eis + (size_t)r * 2 * E + E;
    int e0 = k * CH, n = min(CH, E - e0);
    for (int b = threadIdx.x; b < NBUCK; b += BS) hist[b] = 0;
    __syncthreads();
    for (int i = threadIdx.x; i < n; i += BS)
        atomicAdd(&hist[dstp[e0 + i] >> SH], 1);
    __syncthreads();
    for (int b = threadIdx.x; b < NBUCK; b += BS)
        T[(r * NBUCK + b) * NBKr + k] = hist[b];
}

// ---------------- exclusive scan (3-kernel, n-parametrized) ----------------
__global__ void k_scanA(const int* __restrict__ in, int* __restrict__ out,
                        int* __restrict__ blksum, int n) {
    __shared__ int sh[BS];
    int t = blockIdx.x * BS + threadIdx.x;
    int v = (t < n) ? in[t] : 0;
    sh[threadIdx.x] = v;
    __syncthreads();
#pragma unroll
    for (int d = 1; d < BS; d <<= 1) {
        int x = (threadIdx.x >= d) ? sh[threadIdx.x - d] : 0;
        __syncthreads();
        sh[threadIdx.x] += x;
        __syncthreads();
    }
    int incl = sh[threadIdx.x];
    if (t < n) out[t] = incl - v;
    if (threadIdx.x == BS - 1) blksum[blockIdx.x] = incl;
}

__global__ void k_scanB(int* __restrict__ blksum, int nb) {
    __shared__ int sh[BS];
    __shared__ int carry;
    if (threadIdx.x == 0) carry = 0;
    __syncthreads();
    for (int base = 0; base < nb; base += BS) {
        int t = base + threadIdx.x;
        int v = (t < nb) ? blksum[t] : 0;
        sh[threadIdx.x] = v;
        __syncthreads();
#pragma unroll
        for (int d = 1; d < BS; d <<= 1) {
            int x = (threadIdx.x >= d) ? sh[threadIdx.x - d] : 0;
            __syncthreads();
            sh[threadIdx.x] += x;
            __syncthreads();
        }
        int incl = sh[threadIdx.x];
        if (t < nb) blksum[t] = incl - v + carry;
        __syncthreads();
        if (threadIdx.x == BS - 1) carry += incl;
        __syncthreads();
    }
}

__global__ void k_scanC(int* __restrict__ out, const int* __restrict__ blksum, int n) {
    int t = blockIdx.x * BS + threadIdx.x;
    if (t < n) out[t] += blksum[blockIdx.x];
}

// ---------------- partition: LDS-staged scatter, coalesced emission ----------
__global__ void k_scat(const int* __restrict__ eis, const int* __restrict__ T,
                       int* __restrict__ binned) {
    __shared__ int hist[NBUCK], lstart[NBUCK], cursor[NBUCK], gbase[NBUCK];
    __shared__ int sc[BS];
    __shared__ int shuf[CH];              // 32 KB
    __shared__ unsigned char bkt[CH];     // 8 KB
    int r = blockIdx.x / NBKr, k = blockIdx.x - r * NBKr;
    const int* srcp = eis + (size_t)r * 2 * E;
    const int* dstp = srcp + E;
    int e0 = k * CH, n = min(CH, E - e0);
    for (int b = threadIdx.x; b < NBUCK; b += BS) hist[b] = 0;
    __syncthreads();
    for (int i = threadIdx.x; i < n; i += BS)
        atomicAdd(&hist[dstp[e0 + i] >> SH], 1);
    __syncthreads();
    // exclusive prefix over NBUCK (<= BS) entries
    int v = (threadIdx.x < NBUCK) ? hist[threadIdx.x] : 0;
    sc[threadIdx.x] = v;
    __syncthreads();
#pragma unroll
    for (int d = 1; d < BS; d <<= 1) {
        int x = (threadIdx.x >= d) ? sc[threadIdx.x - d] : 0;
        __syncthreads();
        sc[threadIdx.x] += x;
        __syncthreads();
    }
    if (threadIdx.x < NBUCK) {
        int ex = sc[threadIdx.x] - v;
        lstart[threadIdx.x] = ex;
        cursor[threadIdx.x] = ex;
        gbase[threadIdx.x]  = T[(r * NBUCK + threadIdx.x) * NBKr + k];
    }
    __syncthreads();
    // local scatter into LDS (bucket-ordered)
    for (int i = threadIdx.x; i < n; i += BS) {
        int d = dstp[e0 + i];
        int b = d >> SH;
        int pos = atomicAdd(&cursor[b], 1);
        shuf[pos] = ((d & (BSPAN - 1)) << 17) | srcp[e0 + i];   // src < 2^17
        bkt[pos]  = (unsigned char)b;
    }
    __syncthreads();
    // coalesced emission: consecutive i -> (mostly) consecutive global dest
    for (int i = threadIdx.x; i < n; i += BS) {
        int b = bkt[i];
        binned[gbase[b] + (i - lstart[b])] = shuf[i];
    }
}

// ---------------- per-bucket degree -> dinv ----------------
__global__ void k_deg(const int* __restrict__ T, const int* __restrict__ binned,
                      float* __restrict__ dinv) {
    __shared__ int deg[BSPAN];
    int gb = blockIdx.x;
    int r = gb / NBUCK, b = gb - r * NBUCK;
    int start = T[gb * NBKr];
    int end = (gb == RB - 1) ? TOTE : T[(gb + 1) * NBKr];
    for (int t = threadIdx.x; t < BSPAN; t += BS) deg[t] = 0;
    __syncthreads();
    for (int i = start + threadIdx.x; i < end; i += BS)
        atomicAdd(&deg[((unsigned)binned[i]) >> 17], 1);
    __syncthreads();
    int lo = b << SH;
    int nn = min(BSPAN, N - lo);
    for (int t = threadIdx.x; t < nn; t += BS)
        dinv[r * N + lo + t] = rsqrtf((float)deg[t] + 1.0f);
}

// ---------------- layer 1: per-bucket LDS accumulate + relu + wrow dot ------
__global__ __launch_bounds__(512)
void k_l1b(const int* __restrict__ T, const int* __restrict__ binned,
           const float* __restrict__ dinv, const float* __restrict__ H0,
           const float* __restrict__ b1, const float* __restrict__ W2,
           float* __restrict__ g) {
    __shared__ float acc[BSPAN * HID];   // 64 KB
    int gb = blockIdx.x;
    int r = gb / NBUCK, b = gb - r * NBUCK;
    int rbase = r * N;
    int start = T[gb * NBKr];
    int end = (gb == RB - 1) ? TOTE : T[(gb + 1) * NBKr];
    for (int t = threadIdx.x; t < BSPAN * HID; t += 512) acc[t] = 0.f;
    __syncthreads();
    int j = threadIdx.x & 31;
    for (int rec = start + (threadIdx.x >> 5); rec < end; rec += 16) {
        int rc = binned[rec];                       // broadcast across 32 lanes
        int s = rc & 0x1FFFF;
        int dl = ((unsigned)rc) >> 17;
        // 128B coalesced H0 gather; LDS row = banks 0..31 (conflict-free)
        atomicAdd(&acc[(dl << 5) + j], dinv[rbase + s] * H0[(s << 5) + j]);
    }
    __syncthreads();
    int lo = b << SH;
    int nn = min(BSPAN, N - lo);
    float wr = 0.f;
#pragma unroll
    for (int kk = 0; kk < EMB; ++kk) wr += W2[j * EMB + kk];   // wrow[j], L1
    for (int t = threadIdx.x; t < (nn << 5); t += 512) {       // t&31 == j
        int node = lo + (t >> 5);
        float di = dinv[rbase + node];
        float h = fmaxf(di * acc[t] + di * di * H0[(node << 5) + j] + b1[j], 0.f);
        float p = h * wr;
#pragma unroll
        for (int o = 16; o > 0; o >>= 1) p += __shfl_xor(p, o, 32);
        if (j == 0) g[rbase + node] = p;
    }
}

// ---------------- layer 2: per-bucket scalar LDS accumulate + finalize ------
__global__ void k_l2b(const int* __restrict__ T, const int* __restrict__ binned,
                      const float* __restrict__ dinv, const float* __restrict__ g,
                      const float* __restrict__ b2, float* __restrict__ out) {
    __shared__ float sacc[BSPAN];
    int gb = blockIdx.x;
    int r = gb / NBUCK, b = gb - r * NBUCK;
    int rbase = r * N;
    int start = T[gb * NBKr];
    int end = (gb == RB - 1) ? TOTE : T[(gb + 1) * NBKr];
    for (int t = threadIdx.x; t < BSPAN; t += BS) sacc[t] = 0.f;
    __syncthreads();
    for (int i = start + threadIdx.x; i < end; i += BS) {
        int rc = binned[i];
        int s = rc & 0x1FFFF;
        atomicAdd(&sacc[((unsigned)rc) >> 17], dinv[rbase + s] * g[rbase + s]);
    }
    __syncthreads();
    float sb = 0.f;
#pragma unroll
    for (int kk = 0; kk < EMB; ++kk) sb += b2[kk];
    int lo = b << SH;
    int nn = min(BSPAN, N - lo);
    for (int t = threadIdx.x; t < nn; t += BS) {
        float di = dinv[rbase + lo + t];
        out[rbase + lo + t] = di * (sacc[t] + di * g[rbase + lo + t]) + sb;
    }
}

extern "C" void kernel_launch(void* const* d_in, const int* in_sizes, int n_in,
                              void* d_out, int out_size, void* d_ws, size_t ws_size,
                              hipStream_t stream) {
    const float* x  = (const float*)d_in[0];
    const int*  eis = (const int*)d_in[1];
    const float* W1 = (const float*)d_in[2];
    const float* b1 = (const float*)d_in[3];
    const float* W2 = (const float*)d_in[4];
    const float* b2 = (const float*)d_in[5];
    float* out = (float*)d_out;

    // ws (4B units): H0 [N*32] | T [NT] | blksum [2048] | dinv [M] | g [M] |
    //                binned [R*E]   -> ~42.3 MB total
    float* H0     = (float*)d_ws;
    int*   T      = (int*)(H0 + (size_t)N * HID);
    int*   blksum = T + NT;
    float* dinv   = (float*)(blksum + 2048);
    float* g      = dinv + M;
    int*   binned = (int*)(g + M);

    constexpr int NBSCAN = (NT + BS - 1) / BS;   // 601

    k_gemm_h0<<<(N * HID + BS - 1) / BS, BS, 0, stream>>>(x, W1, H0);
    k_hist  <<<R * NBKr, BS, 0, stream>>>(eis, T);
    k_scanA <<<NBSCAN, BS, 0, stream>>>(T, T, blksum, NT);   // in-place ok
    k_scanB <<<1, BS, 0, stream>>>(blksum, NBSCAN);
    k_scanC <<<NBSCAN, BS, 0, stream>>>(T, blksum, NT);
    k_scat  <<<R * NBKr, BS, 0, stream>>>(eis, T, binned);
    k_deg   <<<RB, BS, 0, stream>>>(T, binned, dinv);
    k_l1b   <<<RB, 512, 0, stream>>>(T, binned, dinv, H0, b1, W2, g);
    k_l2b   <<<RB, BS, 0, stream>>>(T, binned, dinv, g, b2, out);
}

// Round 4
// 1737.953 us; speedup vs baseline: 1.0084x; 1.0084x over previous
//
#include <hip/hip_runtime.h>

// EdgeFeatGAE: 2-layer GCN (R=4 relations share x, W1, W2), out = sum over
// embed dim -> [R, N].
// Algebra: layer2 collapses to scalar per node (wrow[j] = sum_k W2[j][k]);
// H0 = x@W1 is relation-independent.
// R3: radix-partition into 512-node dst-buckets (coalesced writes), per-bucket
// LDS accumulation (zero global atomics).
// R4: k_l1b/k_l2b were latency-bound (264 GB/s beyond-L2, VALUBusy 4.7%,
// 1 gather in flight per 32-lane group). 4x record unroll -> 4 independent
// gathers in flight per group.

constexpr int N    = 100000;
constexpr int E    = 1600000;
constexpr int R    = 4;
constexpr int FEAT = 128;
constexpr int HID  = 32;
constexpr int EMB  = 16;
constexpr int M    = R * N;
constexpr int BS   = 256;
constexpr int SH    = 9;                          // bucket = dst >> 9
constexpr int BSPAN = 1 << SH;                    // 512 nodes per bucket
constexpr int NBUCK = (N + BSPAN - 1) / BSPAN;    // 196 buckets per relation
constexpr int CH    = 8192;                       // edges per partition block
constexpr int NBKr  = (E + CH - 1) / CH;          // 196 blocks per relation
constexpr int RB    = R * NBUCK;                  // 784 buckets total
constexpr int NT    = RB * NBKr;                  // 153664 table entries
constexpr int TOTE  = R * E;                      // 6.4M records

// ---------------- H0 = x @ W1  [N,32] ----------------
__global__ void k_gemm_h0(const float* __restrict__ x, const float* __restrict__ W1,
                          float* __restrict__ H0) {
    int t = blockIdx.x * blockDim.x + threadIdx.x;
    if (t >= N * HID) return;
    int j = t & (HID - 1);
    int i = t >> 5;
    const float* xr = x + (size_t)i * FEAT;
    float acc = 0.f;
#pragma unroll 8
    for (int k = 0; k < FEAT; ++k)
        acc = fmaf(xr[k], W1[k * HID + j], acc);
    H0[t] = acc;
}

// ---------------- per-(bucket, block) histogram ----------------
__global__ void k_hist(const int* __restrict__ eis, int* __restrict__ T) {
    __shared__ int hist[NBUCK];
    int r = blockIdx.x / NBKr, k = blockIdx.x - r * NBKr;
    const int* dstp = eis + (size_t)r * 2 * E + E;
    int e0 = k * CH, n = min(CH, E - e0);
    for (int b = threadIdx.x; b < NBUCK; b += BS) hist[b] = 0;
    __syncthreads();
    for (int i = threadIdx.x; i < n; i += BS)
        atomicAdd(&hist[dstp[e0 + i] >> SH], 1);
    __syncthreads();
    for (int b = threadIdx.x; b < NBUCK; b += BS)
        T[(r * NBUCK + b) * NBKr + k] = hist[b];
}

// ---------------- exclusive scan (3-kernel, n-parametrized) ----------------
__global__ void k_scanA(const int* __restrict__ in, int* __restrict__ out,
                        int* __restrict__ blksum, int n) {
    __shared__ int sh[BS];
    int t = blockIdx.x * BS + threadIdx.x;
    int v = (t < n) ? in[t] : 0;
    sh[threadIdx.x] = v;
    __syncthreads();
#pragma unroll
    for (int d = 1; d < BS; d <<= 1) {
        int x = (threadIdx.x >= d) ? sh[threadIdx.x - d] : 0;
        __syncthreads();
        sh[threadIdx.x] += x;
        __syncthreads();
    }
    int incl = sh[threadIdx.x];
    if (t < n) out[t] = incl - v;
    if (threadIdx.x == BS - 1) blksum[blockIdx.x] = incl;
}

__global__ void k_scanB(int* __restrict__ blksum, int nb) {
    __shared__ int sh[BS];
    __shared__ int carry;
    if (threadIdx.x == 0) carry = 0;
    __syncthreads();
    for (int base = 0; base < nb; base += BS) {
        int t = base + threadIdx.x;
        int v = (t < nb) ? blksum[t] : 0;
        sh[threadIdx.x] = v;
        __syncthreads();
#pragma unroll
        for (int d = 1; d < BS; d <<= 1) {
            int x = (threadIdx.x >= d) ? sh[threadIdx.x - d] : 0;
            __syncthreads();
            sh[threadIdx.x] += x;
            __syncthreads();
        }
        int incl = sh[threadIdx.x];
        if (t < nb) blksum[t] = incl - v + carry;
        __syncthreads();
        if (threadIdx.x == BS - 1) carry += incl;
        __syncthreads();
    }
}

__global__ void k_scanC(int* __restrict__ out, const int* __restrict__ blksum, int n) {
    int t = blockIdx.x * BS + threadIdx.x;
    if (t < n) out[t] += blksum[blockIdx.x];
}

// ---------------- partition: LDS-staged scatter, coalesced emission ----------
__global__ void k_scat(const int* __restrict__ eis, const int* __restrict__ T,
                       int* __restrict__ binned) {
    __shared__ int hist[NBUCK], lstart[NBUCK], cursor[NBUCK], gbase[NBUCK];
    __shared__ int sc[BS];
    __shared__ int shuf[CH];              // 32 KB
    __shared__ unsigned char bkt[CH];     // 8 KB
    int r = blockIdx.x / NBKr, k = blockIdx.x - r * NBKr;
    const int* srcp = eis + (size_t)r * 2 * E;
    const int* dstp = srcp + E;
    int e0 = k * CH, n = min(CH, E - e0);
    for (int b = threadIdx.x; b < NBUCK; b += BS) hist[b] = 0;
    __syncthreads();
    for (int i = threadIdx.x; i < n; i += BS)
        atomicAdd(&hist[dstp[e0 + i] >> SH], 1);
    __syncthreads();
    // exclusive prefix over NBUCK (<= BS) entries
    int v = (threadIdx.x < NBUCK) ? hist[threadIdx.x] : 0;
    sc[threadIdx.x] = v;
    __syncthreads();
#pragma unroll
    for (int d = 1; d < BS; d <<= 1) {
        int x = (threadIdx.x >= d) ? sc[threadIdx.x - d] : 0;
        __syncthreads();
        sc[threadIdx.x] += x;
        __syncthreads();
    }
    if (threadIdx.x < NBUCK) {
        int ex = sc[threadIdx.x] - v;
        lstart[threadIdx.x] = ex;
        cursor[threadIdx.x] = ex;
        gbase[threadIdx.x]  = T[(r * NBUCK + threadIdx.x) * NBKr + k];
    }
    __syncthreads();
    // local scatter into LDS (bucket-ordered)
    for (int i = threadIdx.x; i < n; i += BS) {
        int d = dstp[e0 + i];
        int b = d >> SH;
        int pos = atomicAdd(&cursor[b], 1);
        shuf[pos] = ((d & (BSPAN - 1)) << 17) | srcp[e0 + i];   // src < 2^17
        bkt[pos]  = (unsigned char)b;
    }
    __syncthreads();
    // coalesced emission: consecutive i -> (mostly) consecutive global dest
    for (int i = threadIdx.x; i < n; i += BS) {
        int b = bkt[i];
        binned[gbase[b] + (i - lstart[b])] = shuf[i];
    }
}

// ---------------- per-bucket degree -> dinv ----------------
__global__ void k_deg(const int* __restrict__ T, const int* __restrict__ binned,
                      float* __restrict__ dinv) {
    __shared__ int deg[BSPAN];
    int gb = blockIdx.x;
    int r = gb / NBUCK, b = gb - r * NBUCK;
    int start = T[gb * NBKr];
    int end = (gb == RB - 1) ? TOTE : T[(gb + 1) * NBKr];
    for (int t = threadIdx.x; t < BSPAN; t += BS) deg[t] = 0;
    __syncthreads();
    for (int i = start + threadIdx.x; i < end; i += BS)
        atomicAdd(&deg[((unsigned)binned[i]) >> 17], 1);
    __syncthreads();
    int lo = b << SH;
    int nn = min(BSPAN, N - lo);
    for (int t = threadIdx.x; t < nn; t += BS)
        dinv[r * N + lo + t] = rsqrtf((float)deg[t] + 1.0f);
}

// ---------------- layer 1: per-bucket LDS accumulate + relu + wrow dot ------
// R4: 4-record unroll per 32-lane group -> 4 independent H0 gathers in flight.
__global__ __launch_bounds__(512)
void k_l1b(const int* __restrict__ T, const int* __restrict__ binned,
           const float* __restrict__ dinv, const float* __restrict__ H0,
           const float* __restrict__ b1, const float* __restrict__ W2,
           float* __restrict__ g) {
    __shared__ float acc[BSPAN * HID];   // 64 KB
    int gb = blockIdx.x;
    int r = gb / NBUCK, b = gb - r * NBUCK;
    int rbase = r * N;
    int start = T[gb * NBKr];
    int end = (gb == RB - 1) ? TOTE : T[(gb + 1) * NBKr];
    for (int t = threadIdx.x; t < BSPAN * HID; t += 512) acc[t] = 0.f;
    __syncthreads();
    int j = threadIdx.x & 31;
    int g32 = threadIdx.x >> 5;          // 0..15
    int rec = start + g32;
    // main loop: 4 records per group-iteration (stride 64 over record space)
    for (; rec + 48 < end; rec += 64) {
        int rc0 = binned[rec];
        int rc1 = binned[rec + 16];
        int rc2 = binned[rec + 32];
        int rc3 = binned[rec + 48];
        int s0 = rc0 & 0x1FFFF, s1 = rc1 & 0x1FFFF;
        int s2 = rc2 & 0x1FFFF, s3 = rc3 & 0x1FFFF;
        float d0 = dinv[rbase + s0], d1 = dinv[rbase + s1];
        float d2 = dinv[rbase + s2], d3 = dinv[rbase + s3];
        float h0v = H0[(s0 << 5) + j], h1v = H0[(s1 << 5) + j];
        float h2v = H0[(s2 << 5) + j], h3v = H0[(s3 << 5) + j];
        atomicAdd(&acc[((((unsigned)rc0) >> 17) << 5) + j], d0 * h0v);
        atomicAdd(&acc[((((unsigned)rc1) >> 17) << 5) + j], d1 * h1v);
        atomicAdd(&acc[((((unsigned)rc2) >> 17) << 5) + j], d2 * h2v);
        atomicAdd(&acc[((((unsigned)rc3) >> 17) << 5) + j], d3 * h3v);
    }
    // tail
    for (; rec < end; rec += 16) {
        int rc = binned[rec];
        int s = rc & 0x1FFFF;
        atomicAdd(&acc[((((unsigned)rc) >> 17) << 5) + j],
                  dinv[rbase + s] * H0[(s << 5) + j]);
    }
    __syncthreads();
    int lo = b << SH;
    int nn = min(BSPAN, N - lo);
    float wr = 0.f;
#pragma unroll
    for (int kk = 0; kk < EMB; ++kk) wr += W2[j * EMB + kk];   // wrow[j], L1
    for (int t = threadIdx.x; t < (nn << 5); t += 512) {       // t&31 == j
        int node = lo + (t >> 5);
        float di = dinv[rbase + node];
        float h = fmaxf(di * acc[t] + di * di * H0[(node << 5) + j] + b1[j], 0.f);
        float p = h * wr;
#pragma unroll
        for (int o = 16; o > 0; o >>= 1) p += __shfl_xor(p, o, 32);
        if (j == 0) g[rbase + node] = p;
    }
}

// ---------------- layer 2: per-bucket scalar LDS accumulate + finalize ------
__global__ void k_l2b(const int* __restrict__ T, const int* __restrict__ binned,
                      const float* __restrict__ dinv, const float* __restrict__ g,
                      const float* __restrict__ b2, float* __restrict__ out) {
    __shared__ float sacc[BSPAN];
    int gb = blockIdx.x;
    int r = gb / NBUCK, b = gb - r * NBUCK;
    int rbase = r * N;
    int start = T[gb * NBKr];
    int end = (gb == RB - 1) ? TOTE : T[(gb + 1) * NBKr];
    for (int t = threadIdx.x; t < BSPAN; t += BS) sacc[t] = 0.f;
    __syncthreads();
    int i = start + threadIdx.x;
    for (; i + 3 * BS < end; i += 4 * BS) {
        int rc0 = binned[i], rc1 = binned[i + BS];
        int rc2 = binned[i + 2 * BS], rc3 = binned[i + 3 * BS];
        int s0 = rc0 & 0x1FFFF, s1 = rc1 & 0x1FFFF;
        int s2 = rc2 & 0x1FFFF, s3 = rc3 & 0x1FFFF;
        float v0 = dinv[rbase + s0] * g[rbase + s0];
        float v1 = dinv[rbase + s1] * g[rbase + s1];
        float v2 = dinv[rbase + s2] * g[rbase + s2];
        float v3 = dinv[rbase + s3] * g[rbase + s3];
        atomicAdd(&sacc[((unsigned)rc0) >> 17], v0);
        atomicAdd(&sacc[((unsigned)rc1) >> 17], v1);
        atomicAdd(&sacc[((unsigned)rc2) >> 17], v2);
        atomicAdd(&sacc[((unsigned)rc3) >> 17], v3);
    }
    for (; i < end; i += BS) {
        int rc = binned[i];
        int s = rc & 0x1FFFF;
        atomicAdd(&sacc[((unsigned)rc) >> 17], dinv[rbase + s] * g[rbase + s]);
    }
    __syncthreads();
    float sb = 0.f;
#pragma unroll
    for (int kk = 0; kk < EMB; ++kk) sb += b2[kk];
    int lo = b << SH;
    int nn = min(BSPAN, N - lo);
    for (int t = threadIdx.x; t < nn; t += BS) {
        float di = dinv[rbase + lo + t];
        out[rbase + lo + t] = di * (sacc[t] + di * g[rbase + lo + t]) + sb;
    }
}

extern "C" void kernel_launch(void* const* d_in, const int* in_sizes, int n_in,
                              void* d_out, int out_size, void* d_ws, size_t ws_size,
                              hipStream_t stream) {
    const float* x  = (const float*)d_in[0];
    const int*  eis = (const int*)d_in[1];
    const float* W1 = (const float*)d_in[2];
    const float* b1 = (const float*)d_in[3];
    const float* W2 = (const float*)d_in[4];
    const float* b2 = (const float*)d_in[5];
    float* out = (float*)d_out;

    // ws (4B units): H0 [N*32] | T [NT] | blksum [2048] | dinv [M] | g [M] |
    //                binned [R*E]   -> ~42.3 MB total
    float* H0     = (float*)d_ws;
    int*   T      = (int*)(H0 + (size_t)N * HID);
    int*   blksum = T + NT;
    float* dinv   = (float*)(blksum + 2048);
    float* g      = dinv + M;
    int*   binned = (int*)(g + M);

    constexpr int NBSCAN = (NT + BS - 1) / BS;   // 601

    k_gemm_h0<<<(N * HID + BS - 1) / BS, BS, 0, stream>>>(x, W1, H0);
    k_hist  <<<R * NBKr, BS, 0, stream>>>(eis, T);
    k_scanA <<<NBSCAN, BS, 0, stream>>>(T, T, blksum, NT);   // in-place ok
    k_scanB <<<1, BS, 0, stream>>>(blksum, NBSCAN);
    k_scanC <<<NBSCAN, BS, 0, stream>>>(T, blksum, NT);
    k_scat  <<<R * NBKr, BS, 0, stream>>>(eis, T, binned);
    k_deg   <<<RB, BS, 0, stream>>>(T, binned, dinv);
    k_l1b   <<<RB, 512, 0, stream>>>(T, binned, dinv, H0, b1, W2, g);
    k_l2b   <<<RB, BS, 0, stream>>>(T, binned, dinv, g, b2, out);
}

// Round 5
// 510.578 us; speedup vs baseline: 3.4326x; 3.4039x over previous
//
#include <hip/hip_runtime.h>

// EdgeFeatGAE: 2-layer GCN (R=4 relations share x, W1, W2), out = sum over
// embed dim -> [R, N].
// Algebra: layer2 collapses to scalar per node (wrow[j] = sum_k W2[j][k]);
// H0 = x@W1 is relation-independent; q[i] = dinv_i * g_i makes layer2 a pure
// scalar gather: out_i = dinv_i*(sum_src q[src] + q[i]) + sum(b2).
// R3: radix-partition into 512-node dst buckets (coalesced writes).
// R5: evidence from R1/R3/R4: per-wave memory concurrency is ~1 chain
// regardless of unrolling -> pack 16 records into each gather instruction
// (4 lanes x 16B fp16 row chunks), full per-node CSR (k_sort2, LDS counting
// sort), register accumulation (no 64KB LDS acc -> occupancy restored),
// fp16 H0 (6.4MB, mostly L2-resident).

constexpr int N    = 100000;
constexpr int E    = 1600000;
constexpr int R    = 4;
constexpr int FEAT = 128;
constexpr int HID  = 32;
constexpr int EMB  = 16;
constexpr int M    = R * N;
constexpr int BS   = 256;
constexpr int SH    = 9;                          // bucket = dst >> 9
constexpr int BSPAN = 1 << SH;                    // 512 nodes per bucket
constexpr int NBUCK = (N + BSPAN - 1) / BSPAN;    // 196 buckets per relation
constexpr int CH    = 8192;                       // edges per partition block
constexpr int NBKr  = (E + CH - 1) / CH;          // 196 blocks per relation
constexpr int RB    = R * NBUCK;                  // 784 buckets total
constexpr int NT    = RB * NBKr;                  // 153664 table entries
constexpr int TOTE  = R * E;                      // 6.4M records

typedef _Float16 half8 __attribute__((ext_vector_type(8)));   // 16B chunk

// ---------------- H0 = x @ W1  [N,32] -> fp16 ----------------
__global__ void k_gemm_h0(const float* __restrict__ x, const float* __restrict__ W1,
                          _Float16* __restrict__ H0h) {
    int t = blockIdx.x * blockDim.x + threadIdx.x;
    if (t >= N * HID) return;
    int j = t & (HID - 1);
    int i = t >> 5;
    const float* xr = x + (size_t)i * FEAT;
    float acc = 0.f;
#pragma unroll 8
    for (int k = 0; k < FEAT; ++k)
        acc = fmaf(xr[k], W1[k * HID + j], acc);
    H0h[t] = (_Float16)acc;
}

// ---------------- wrow[j] = sum_k W2[j][k]; wrowbuf[32] = sum(b2) ----------
__global__ void k_wrow(const float* __restrict__ W2, const float* __restrict__ b2,
                       float* __restrict__ wrowbuf) {
    int j = threadIdx.x;
    if (j < HID) {
        float s = 0.f;
#pragma unroll
        for (int k = 0; k < EMB; ++k) s += W2[j * EMB + k];
        wrowbuf[j] = s;
    } else if (j == HID) {
        float s = 0.f;
#pragma unroll
        for (int k = 0; k < EMB; ++k) s += b2[k];
        wrowbuf[HID] = s;
    }
}

// ---------------- per-(bucket, block) histogram ----------------
__global__ void k_hist(const int* __restrict__ eis, int* __restrict__ T) {
    __shared__ int hist[NBUCK];
    int r = blockIdx.x / NBKr, k = blockIdx.x - r * NBKr;
    const int* dstp = eis + (size_t)r * 2 * E + E;
    int e0 = k * CH, n = min(CH, E - e0);
    for (int b = threadIdx.x; b < NBUCK; b += BS) hist[b] = 0;
    __syncthreads();
    for (int i = threadIdx.x; i < n; i += BS)
        atomicAdd(&hist[dstp[e0 + i] >> SH], 1);
    __syncthreads();
    for (int b = threadIdx.x; b < NBUCK; b += BS)
        T[(r * NBUCK + b) * NBKr + k] = hist[b];
}

// ---------------- exclusive scan (3-kernel, n-parametrized) ----------------
__global__ void k_scanA(const int* __restrict__ in, int* __restrict__ out,
                        int* __restrict__ blksum, int n) {
    __shared__ int sh[BS];
    int t = blockIdx.x * BS + threadIdx.x;
    int v = (t < n) ? in[t] : 0;
    sh[threadIdx.x] = v;
    __syncthreads();
#pragma unroll
    for (int d = 1; d < BS; d <<= 1) {
        int x = (threadIdx.x >= d) ? sh[threadIdx.x - d] : 0;
        __syncthreads();
        sh[threadIdx.x] += x;
        __syncthreads();
    }
    int incl = sh[threadIdx.x];
    if (t < n) out[t] = incl - v;
    if (threadIdx.x == BS - 1) blksum[blockIdx.x] = incl;
}

__global__ void k_scanB(int* __restrict__ blksum, int nb) {
    __shared__ int sh[BS];
    __shared__ int carry;
    if (threadIdx.x == 0) carry = 0;
    __syncthreads();
    for (int base = 0; base < nb; base += BS) {
        int t = base + threadIdx.x;
        int v = (t < nb) ? blksum[t] : 0;
        sh[threadIdx.x] = v;
        __syncthreads();
#pragma unroll
        for (int d = 1; d < BS; d <<= 1) {
            int x = (threadIdx.x >= d) ? sh[threadIdx.x - d] : 0;
            __syncthreads();
            sh[threadIdx.x] += x;
            __syncthreads();
        }
        int incl = sh[threadIdx.x];
        if (t < nb) blksum[t] = incl - v + carry;
        __syncthreads();
        if (threadIdx.x == BS - 1) carry += incl;
        __syncthreads();
    }
}

__global__ void k_scanC(int* __restrict__ out, const int* __restrict__ blksum, int n) {
    int t = blockIdx.x * BS + threadIdx.x;
    if (t < n) out[t] += blksum[blockIdx.x];
}

// ---------------- partition: LDS-staged scatter, coalesced emission ----------
__global__ void k_scat(const int* __restrict__ eis, const int* __restrict__ T,
                       int* __restrict__ binned) {
    __shared__ int hist[NBUCK], lstart[NBUCK], cursor[NBUCK], gbase[NBUCK];
    __shared__ int sc[BS];
    __shared__ int shuf[CH];              // 32 KB
    __shared__ unsigned char bkt[CH];     // 8 KB
    int r = blockIdx.x / NBKr, k = blockIdx.x - r * NBKr;
    const int* srcp = eis + (size_t)r * 2 * E;
    const int* dstp = srcp + E;
    int e0 = k * CH, n = min(CH, E - e0);
    for (int b = threadIdx.x; b < NBUCK; b += BS) hist[b] = 0;
    __syncthreads();
    for (int i = threadIdx.x; i < n; i += BS)
        atomicAdd(&hist[dstp[e0 + i] >> SH], 1);
    __syncthreads();
    int v = (threadIdx.x < NBUCK) ? hist[threadIdx.x] : 0;
    sc[threadIdx.x] = v;
    __syncthreads();
#pragma unroll
    for (int d = 1; d < BS; d <<= 1) {
        int x = (threadIdx.x >= d) ? sc[threadIdx.x - d] : 0;
        __syncthreads();
        sc[threadIdx.x] += x;
        __syncthreads();
    }
    if (threadIdx.x < NBUCK) {
        int ex = sc[threadIdx.x] - v;
        lstart[threadIdx.x] = ex;
        cursor[threadIdx.x] = ex;
        gbase[threadIdx.x]  = T[(r * NBUCK + threadIdx.x) * NBKr + k];
    }
    __syncthreads();
    for (int i = threadIdx.x; i < n; i += BS) {
        int d = dstp[e0 + i];
        int b = d >> SH;
        int pos = atomicAdd(&cursor[b], 1);
        shuf[pos] = ((d & (BSPAN - 1)) << 17) | srcp[e0 + i];   // src < 2^17
        bkt[pos]  = (unsigned char)b;
    }
    __syncthreads();
    for (int i = threadIdx.x; i < n; i += BS) {
        int b = bkt[i];
        binned[gbase[b] + (i - lstart[b])] = shuf[i];
    }
}

// ---------------- per-bucket counting sort -> exact CSR + dinv --------------
__global__ __launch_bounds__(BSPAN)
void k_sort2(const int* __restrict__ T, const int* __restrict__ binned,
             int* __restrict__ ssrc, int* __restrict__ off, int* __restrict__ cnt,
             float* __restrict__ dinv) {
    __shared__ int hist[BSPAN], cur[BSPAN], sc[BSPAN];
    int gb = blockIdx.x;
    int r = gb / NBUCK, b = gb - r * NBUCK;
    int start = T[gb * NBKr];
    int end = (gb == RB - 1) ? TOTE : T[(gb + 1) * NBKr];
    int tid = threadIdx.x;            // 0..511
    hist[tid] = 0;
    __syncthreads();
    for (int i = start + tid; i < end; i += BSPAN)
        atomicAdd(&hist[((unsigned)binned[i]) >> 17], 1);
    __syncthreads();
    int v = hist[tid];
    sc[tid] = v;
    __syncthreads();
#pragma unroll
    for (int d = 1; d < BSPAN; d <<= 1) {
        int x = (tid >= d) ? sc[tid - d] : 0;
        __syncthreads();
        sc[tid] += x;
        __syncthreads();
    }
    int ex = sc[tid] - v;
    cur[tid] = start + ex;
    int node = (b << SH) + tid;
    if (node < N) {
        int ri = r * N + node;
        off[ri] = start + ex;
        cnt[ri] = v;
        dinv[ri] = rsqrtf((float)v + 1.0f);
    }
    __syncthreads();
    // scatter src into per-node segments (random 4B writes in a 32KB window)
    for (int i = start + tid; i < end; i += BSPAN) {
        int rc = binned[i];
        int pos = atomicAdd(&cur[((unsigned)rc) >> 17], 1);
        ssrc[pos] = rc & 0x1FFFF;
    }
}

// ---------------- layer 1: 32 lanes/node, 4 lanes/record, register acc ------
// One wave64 gather instruction carries 16 random 64B fp16 rows.
__global__ void k_l1(const int* __restrict__ off, const int* __restrict__ cnt,
                     const int* __restrict__ ssrc, const float* __restrict__ dinv,
                     const half8* __restrict__ H0h, const float* __restrict__ b1,
                     const float* __restrict__ wrowbuf, float* __restrict__ q) {
    int t = blockIdx.x * blockDim.x + threadIdx.x;
    int ri = t >> 5;
    if (ri >= M) return;
    int lane = t & 31;
    int c   = lane & 3;        // 16B chunk of the 64B row
    int sub = lane >> 2;       // record slot 0..7
    int i = ri % N;
    int rbase = ri - i;
    float di = dinv[ri];
    half8 hs = H0h[i * 4 + c];                 // self row chunk
    float acc[8];
#pragma unroll
    for (int kk = 0; kk < 8; ++kk) acc[kk] = 0.f;
    int base = off[ri], n = cnt[ri];
    for (int k0 = 0; k0 < n; k0 += 32) {
        int sb_ = (k0 + lane < n) ? ssrc[base + k0 + lane] : 0;   // coalesced
        int m = n - k0;                         // records left in this window
        for (int bq = 0; bq < 4 && bq * 8 < m; ++bq) {
            int slot = bq * 8 + sub;
            int sj = __shfl(sb_, slot, 32);
            float dv = (slot < m) ? dinv[rbase + sj] : 0.f;
            half8 h = H0h[sj * 4 + c];          // 16B/lane -> 16 rows per wave instr
#pragma unroll
            for (int kk = 0; kk < 8; ++kk)
                acc[kk] = fmaf(dv, (float)h[kk], acc[kk]);
        }
    }
    // reduce over record slots (lanes c, c+4, ..., c+28 hold same chunk)
#pragma unroll
    for (int o = 4; o <= 16; o <<= 1)
#pragma unroll
        for (int kk = 0; kk < 8; ++kk) acc[kk] += __shfl_xor(acc[kk], o, 32);
    // epilogue: h1 = relu(di*acc + di^2*H0self + b1); p = h1 . wrow
    float di2 = di * di;
    float p = 0.f;
#pragma unroll
    for (int kk = 0; kk < 8; ++kk) {
        int j = c * 8 + kk;
        float h1 = fmaf(di, acc[kk], fmaf(di2, (float)hs[kk], b1[j]));
        h1 = fmaxf(h1, 0.f);
        p = fmaf(h1, wrowbuf[j], p);
    }
    p += __shfl_xor(p, 1, 32);
    p += __shfl_xor(p, 2, 32);
    if (lane == 0) q[ri] = di * p;              // q = dinv * g
}

// ---------------- layer 2: per-lane scalar gathers of q + finalize ----------
__global__ void k_l2(const int* __restrict__ off, const int* __restrict__ cnt,
                     const int* __restrict__ ssrc, const float* __restrict__ dinv,
                     const float* __restrict__ q, const float* __restrict__ wrowbuf,
                     float* __restrict__ out) {
    int t = blockIdx.x * blockDim.x + threadIdx.x;
    int ri = t >> 5;
    if (ri >= M) return;
    int lane = t & 31;
    int i = ri % N;
    int rbase = ri - i;
    int base = off[ri], n = cnt[ri];
    float val = 0.f;
    for (int idx = lane; idx < n; idx += 32) {
        int s = ssrc[base + idx];               // coalesced
        val += q[rbase + s];                    // 4B gather, 1.6MB L2-resident
    }
#pragma unroll
    for (int o = 16; o > 0; o >>= 1) val += __shfl_xor(val, o, 32);
    if (lane == 0)
        out[ri] = dinv[ri] * (val + q[ri]) + wrowbuf[HID];
}

extern "C" void kernel_launch(void* const* d_in, const int* in_sizes, int n_in,
                              void* d_out, int out_size, void* d_ws, size_t ws_size,
                              hipStream_t stream) {
    const float* x  = (const float*)d_in[0];
    const int*  eis = (const int*)d_in[1];
    const float* W1 = (const float*)d_in[2];
    const float* b1 = (const float*)d_in[3];
    const float* W2 = (const float*)d_in[4];
    const float* b2 = (const float*)d_in[5];
    float* out = (float*)d_out;

    // ws (4B units): H0h [N*32 halves = N*16] | T [NT] | blksum [2048] |
    //   dinv [M] | q [M] | off [M] | cnt [M] | wrowbuf [64] |
    //   binned [R*E] | ssrc [R*E]   -> ~64.6 MB
    _Float16* H0h = (_Float16*)d_ws;
    int*   T      = (int*)((float*)d_ws + (size_t)N * HID / 2);
    int*   blksum = T + NT;
    float* dinv   = (float*)(blksum + 2048);
    float* q      = dinv + M;
    int*   off    = (int*)(q + M);
    int*   cnt    = off + M;
    float* wrowbuf = (float*)(cnt + M);
    int*   binned = (int*)(wrowbuf + 64);
    int*   ssrc   = binned + TOTE;

    constexpr int NBSCAN = (NT + BS - 1) / BS;   // 601

    k_gemm_h0<<<(N * HID + BS - 1) / BS, BS, 0, stream>>>(x, W1, H0h);
    k_wrow  <<<1, 64, 0, stream>>>(W2, b2, wrowbuf);
    k_hist  <<<R * NBKr, BS, 0, stream>>>(eis, T);
    k_scanA <<<NBSCAN, BS, 0, stream>>>(T, T, blksum, NT);   // in-place ok
    k_scanB <<<1, BS, 0, stream>>>(blksum, NBSCAN);
    k_scanC <<<NBSCAN, BS, 0, stream>>>(T, blksum, NT);
    k_scat  <<<R * NBKr, BS, 0, stream>>>(eis, T, binned);
    k_sort2 <<<RB, BSPAN, 0, stream>>>(T, binned, ssrc, off, cnt, dinv);
    k_l1    <<<(M * 32 + BS - 1) / BS, BS, 0, stream>>>(off, cnt, ssrc, dinv,
                                                        (const half8*)H0h, b1, wrowbuf, q);
    k_l2    <<<(M * 32 + BS - 1) / BS, BS, 0, stream>>>(off, cnt, ssrc, dinv, q,
                                                        wrowbuf, out);
}

// Round 7
// 481.402 us; speedup vs baseline: 3.6407x; 1.0606x over previous
//
#include <hip/hip_runtime.h>

// EdgeFeatGAE: 2-layer GCN (R=4 relations share x, W1, W2), out = sum over
// embed dim -> [R, N].
// Algebra: layer2 collapses to scalar per node (wrow[j] = sum_k W2[j][k]);
// H0 = x@W1 is relation-independent; q[i] = dinv_i * g_i makes layer2 a pure
// scalar gather: out_i = dinv_i*(sum_src q[src] + q[i]) + sum(b2).
// R3: radix-partition into 512-node dst buckets (coalesced writes).
// R5: pack 16 records per wave gather instr (4 lanes x 16B fp16 row chunks),
// exact CSR via per-bucket counting sort, register accumulation. 1738->510us.
// R6: k_gemm_h0 was load-issue-bound (12.8M scalar loads ~= 106us; VALU 12%,
// BW 3.6%). Rewritten: 8 outputs/thread, float4 loads -> 1.8M load instrs.
// R7: resubmit of R6 (GPU broker timeout — never benched).

constexpr int N    = 100000;
constexpr int E    = 1600000;
constexpr int R    = 4;
constexpr int FEAT = 128;
constexpr int HID  = 32;
constexpr int EMB  = 16;
constexpr int M    = R * N;
constexpr int BS   = 256;
constexpr int SH    = 9;                          // bucket = dst >> 9
constexpr int BSPAN = 1 << SH;                    // 512 nodes per bucket
constexpr int NBUCK = (N + BSPAN - 1) / BSPAN;    // 196 buckets per relation
constexpr int CH    = 8192;                       // edges per partition block
constexpr int NBKr  = (E + CH - 1) / CH;          // 196 blocks per relation
constexpr int RB    = R * NBUCK;                  // 784 buckets total
constexpr int NT    = RB * NBKr;                  // 153664 table entries
constexpr int TOTE  = R * E;                      // 6.4M records

typedef _Float16 half8 __attribute__((ext_vector_type(8)));   // 16B chunk

// ---------------- H0 = x @ W1  [N,32] -> fp16 ----------------
// R6: thread = (node, j-octet). 32 float4 x-loads + 256 float4 W1-loads
// (L1-resident) + 1024 FMAs per thread. Coalesced 16B half8 store.
__global__ void k_gemm_h0(const float* __restrict__ x, const float* __restrict__ W1,
                          _Float16* __restrict__ H0h) {
    int t = blockIdx.x * blockDim.x + threadIdx.x;
    if (t >= N * 4) return;
    int i = t >> 2;            // node
    int jh = t & 3;            // j-octet: j = jh*8
    const float4* xr = (const float4*)(x + (size_t)i * FEAT);
    float acc[8];
#pragma unroll
    for (int kk = 0; kk < 8; ++kk) acc[kk] = 0.f;
#pragma unroll 4
    for (int k4 = 0; k4 < FEAT / 4; ++k4) {
        float4 xv = xr[k4];
        float xk[4] = {xv.x, xv.y, xv.z, xv.w};
        const float* wb = W1 + (k4 * 4) * HID + (jh << 3);
#pragma unroll
        for (int dk = 0; dk < 4; ++dk) {
            float4 wlo = *(const float4*)(wb + dk * HID);
            float4 whi = *(const float4*)(wb + dk * HID + 4);
            acc[0] = fmaf(xk[dk], wlo.x, acc[0]);
            acc[1] = fmaf(xk[dk], wlo.y, acc[1]);
            acc[2] = fmaf(xk[dk], wlo.z, acc[2]);
            acc[3] = fmaf(xk[dk], wlo.w, acc[3]);
            acc[4] = fmaf(xk[dk], whi.x, acc[4]);
            acc[5] = fmaf(xk[dk], whi.y, acc[5]);
            acc[6] = fmaf(xk[dk], whi.z, acc[6]);
            acc[7] = fmaf(xk[dk], whi.w, acc[7]);
        }
    }
    half8 hv;
#pragma unroll
    for (int kk = 0; kk < 8; ++kk) hv[kk] = (_Float16)acc[kk];
    ((half8*)H0h)[i * 4 + jh] = hv;    // 16B store, coalesced across lanes
}

// ---------------- wrow[j] = sum_k W2[j][k]; wrowbuf[32] = sum(b2) ----------
__global__ void k_wrow(const float* __restrict__ W2, const float* __restrict__ b2,
                       float* __restrict__ wrowbuf) {
    int j = threadIdx.x;
    if (j < HID) {
        float s = 0.f;
#pragma unroll
        for (int k = 0; k < EMB; ++k) s += W2[j * EMB + k];
        wrowbuf[j] = s;
    } else if (j == HID) {
        float s = 0.f;
#pragma unroll
        for (int k = 0; k < EMB; ++k) s += b2[k];
        wrowbuf[HID] = s;
    }
}

// ---------------- per-(bucket, block) histogram ----------------
__global__ void k_hist(const int* __restrict__ eis, int* __restrict__ T) {
    __shared__ int hist[NBUCK];
    int r = blockIdx.x / NBKr, k = blockIdx.x - r * NBKr;
    const int* dstp = eis + (size_t)r * 2 * E + E;
    int e0 = k * CH, n = min(CH, E - e0);
    for (int b = threadIdx.x; b < NBUCK; b += BS) hist[b] = 0;
    __syncthreads();
    for (int i = threadIdx.x; i < n; i += BS)
        atomicAdd(&hist[dstp[e0 + i] >> SH], 1);
    __syncthreads();
    for (int b = threadIdx.x; b < NBUCK; b += BS)
        T[(r * NBUCK + b) * NBKr + k] = hist[b];
}

// ---------------- exclusive scan (3-kernel, n-parametrized) ----------------
__global__ void k_scanA(const int* __restrict__ in, int* __restrict__ out,
                        int* __restrict__ blksum, int n) {
    __shared__ int sh[BS];
    int t = blockIdx.x * BS + threadIdx.x;
    int v = (t < n) ? in[t] : 0;
    sh[threadIdx.x] = v;
    __syncthreads();
#pragma unroll
    for (int d = 1; d < BS; d <<= 1) {
        int x = (threadIdx.x >= d) ? sh[threadIdx.x - d] : 0;
        __syncthreads();
        sh[threadIdx.x] += x;
        __syncthreads();
    }
    int incl = sh[threadIdx.x];
    if (t < n) out[t] = incl - v;
    if (threadIdx.x == BS - 1) blksum[blockIdx.x] = incl;
}

__global__ void k_scanB(int* __restrict__ blksum, int nb) {
    __shared__ int sh[BS];
    __shared__ int carry;
    if (threadIdx.x == 0) carry = 0;
    __syncthreads();
    for (int base = 0; base < nb; base += BS) {
        int t = base + threadIdx.x;
        int v = (t < nb) ? blksum[t] : 0;
        sh[threadIdx.x] = v;
        __syncthreads();
#pragma unroll
        for (int d = 1; d < BS; d <<= 1) {
            int x = (threadIdx.x >= d) ? sh[threadIdx.x - d] : 0;
            __syncthreads();
            sh[threadIdx.x] += x;
            __syncthreads();
        }
        int incl = sh[threadIdx.x];
        if (t < nb) blksum[t] = incl - v + carry;
        __syncthreads();
        if (threadIdx.x == BS - 1) carry += incl;
        __syncthreads();
    }
}

__global__ void k_scanC(int* __restrict__ out, const int* __restrict__ blksum, int n) {
    int t = blockIdx.x * BS + threadIdx.x;
    if (t < n) out[t] += blksum[blockIdx.x];
}

// ---------------- partition: LDS-staged scatter, coalesced emission ----------
__global__ void k_scat(const int* __restrict__ eis, const int* __restrict__ T,
                       int* __restrict__ binned) {
    __shared__ int hist[NBUCK], lstart[NBUCK], cursor[NBUCK], gbase[NBUCK];
    __shared__ int sc[BS];
    __shared__ int shuf[CH];              // 32 KB
    __shared__ unsigned char bkt[CH];     // 8 KB
    int r = blockIdx.x / NBKr, k = blockIdx.x - r * NBKr;
    const int* srcp = eis + (size_t)r * 2 * E;
    const int* dstp = srcp + E;
    int e0 = k * CH, n = min(CH, E - e0);
    for (int b = threadIdx.x; b < NBUCK; b += BS) hist[b] = 0;
    __syncthreads();
    for (int i = threadIdx.x; i < n; i += BS)
        atomicAdd(&hist[dstp[e0 + i] >> SH], 1);
    __syncthreads();
    int v = (threadIdx.x < NBUCK) ? hist[threadIdx.x] : 0;
    sc[threadIdx.x] = v;
    __syncthreads();
#pragma unroll
    for (int d = 1; d < BS; d <<= 1) {
        int x = (threadIdx.x >= d) ? sc[threadIdx.x - d] : 0;
        __syncthreads();
        sc[threadIdx.x] += x;
        __syncthreads();
    }
    if (threadIdx.x < NBUCK) {
        int ex = sc[threadIdx.x] - v;
        lstart[threadIdx.x] = ex;
        cursor[threadIdx.x] = ex;
        gbase[threadIdx.x]  = T[(r * NBUCK + threadIdx.x) * NBKr + k];
    }
    __syncthreads();
    for (int i = threadIdx.x; i < n; i += BS) {
        int d = dstp[e0 + i];
        int b = d >> SH;
        int pos = atomicAdd(&cursor[b], 1);
        shuf[pos] = ((d & (BSPAN - 1)) << 17) | srcp[e0 + i];   // src < 2^17
        bkt[pos]  = (unsigned char)b;
    }
    __syncthreads();
    for (int i = threadIdx.x; i < n; i += BS) {
        int b = bkt[i];
        binned[gbase[b] + (i - lstart[b])] = shuf[i];
    }
}

// ---------------- per-bucket counting sort -> exact CSR + dinv --------------
__global__ __launch_bounds__(BSPAN)
void k_sort2(const int* __restrict__ T, const int* __restrict__ binned,
             int* __restrict__ ssrc, int* __restrict__ off, int* __restrict__ cnt,
             float* __restrict__ dinv) {
    __shared__ int hist[BSPAN], cur[BSPAN], sc[BSPAN];
    int gb = blockIdx.x;
    int r = gb / NBUCK, b = gb - r * NBUCK;
    int start = T[gb * NBKr];
    int end = (gb == RB - 1) ? TOTE : T[(gb + 1) * NBKr];
    int tid = threadIdx.x;            // 0..511
    hist[tid] = 0;
    __syncthreads();
    for (int i = start + tid; i < end; i += BSPAN)
        atomicAdd(&hist[((unsigned)binned[i]) >> 17], 1);
    __syncthreads();
    int v = hist[tid];
    sc[tid] = v;
    __syncthreads();
#pragma unroll
    for (int d = 1; d < BSPAN; d <<= 1) {
        int x = (tid >= d) ? sc[tid - d] : 0;
        __syncthreads();
        sc[tid] += x;
        __syncthreads();
    }
    int ex = sc[tid] - v;
    cur[tid] = start + ex;
    int node = (b << SH) + tid;
    if (node < N) {
        int ri = r * N + node;
        off[ri] = start + ex;
        cnt[ri] = v;
        dinv[ri] = rsqrtf((float)v + 1.0f);
    }
    __syncthreads();
    // scatter src into per-node segments (random 4B writes in a 32KB window)
    for (int i = start + tid; i < end; i += BSPAN) {
        int rc = binned[i];
        int pos = atomicAdd(&cur[((unsigned)rc) >> 17], 1);
        ssrc[pos] = rc & 0x1FFFF;
    }
}

// ---------------- layer 1: 32 lanes/node, 4 lanes/record, register acc ------
// One wave64 gather instruction carries 16 random 64B fp16 rows.
__global__ void k_l1(const int* __restrict__ off, const int* __restrict__ cnt,
                     const int* __restrict__ ssrc, const float* __restrict__ dinv,
                     const half8* __restrict__ H0h, const float* __restrict__ b1,
                     const float* __restrict__ wrowbuf, float* __restrict__ q) {
    int t = blockIdx.x * blockDim.x + threadIdx.x;
    int ri = t >> 5;
    if (ri >= M) return;
    int lane = t & 31;
    int c   = lane & 3;        // 16B chunk of the 64B row
    int sub = lane >> 2;       // record slot 0..7
    int i = ri % N;
    int rbase = ri - i;
    float di = dinv[ri];
    half8 hs = H0h[i * 4 + c];                 // self row chunk
    float acc[8];
#pragma unroll
    for (int kk = 0; kk < 8; ++kk) acc[kk] = 0.f;
    int base = off[ri], n = cnt[ri];
    for (int k0 = 0; k0 < n; k0 += 32) {
        int sb_ = (k0 + lane < n) ? ssrc[base + k0 + lane] : 0;   // coalesced
        int m = n - k0;                         // records left in this window
        for (int bq = 0; bq < 4 && bq * 8 < m; ++bq) {
            int slot = bq * 8 + sub;
            int sj = __shfl(sb_, slot, 32);
            float dv = (slot < m) ? dinv[rbase + sj] : 0.f;
            half8 h = H0h[sj * 4 + c];          // 16B/lane -> 16 rows per wave instr
#pragma unroll
            for (int kk = 0; kk < 8; ++kk)
                acc[kk] = fmaf(dv, (float)h[kk], acc[kk]);
        }
    }
    // reduce over record slots (lanes c, c+4, ..., c+28 hold same chunk)
#pragma unroll
    for (int o = 4; o <= 16; o <<= 1)
#pragma unroll
        for (int kk = 0; kk < 8; ++kk) acc[kk] += __shfl_xor(acc[kk], o, 32);
    // epilogue: h1 = relu(di*acc + di^2*H0self + b1); p = h1 . wrow
    float di2 = di * di;
    float p = 0.f;
#pragma unroll
    for (int kk = 0; kk < 8; ++kk) {
        int j = c * 8 + kk;
        float h1 = fmaf(di, acc[kk], fmaf(di2, (float)hs[kk], b1[j]));
        h1 = fmaxf(h1, 0.f);
        p = fmaf(h1, wrowbuf[j], p);
    }
    p += __shfl_xor(p, 1, 32);
    p += __shfl_xor(p, 2, 32);
    if (lane == 0) q[ri] = di * p;              // q = dinv * g
}

// ---------------- layer 2: per-lane scalar gathers of q + finalize ----------
__global__ void k_l2(const int* __restrict__ off, const int* __restrict__ cnt,
                     const int* __restrict__ ssrc, const float* __restrict__ dinv,
                     const float* __restrict__ q, const float* __restrict__ wrowbuf,
                     float* __restrict__ out) {
    int t = blockIdx.x * blockDim.x + threadIdx.x;
    int ri = t >> 5;
    if (ri >= M) return;
    int lane = t & 31;
    int i = ri % N;
    int rbase = ri - i;
    int base = off[ri], n = cnt[ri];
    float val = 0.f;
    for (int idx = lane; idx < n; idx += 32) {
        int s = ssrc[base + idx];               // coalesced
        val += q[rbase + s];                    // 4B gather, 1.6MB L2-resident
    }
#pragma unroll
    for (int o = 16; o > 0; o >>= 1) val += __shfl_xor(val, o, 32);
    if (lane == 0)
        out[ri] = dinv[ri] * (val + q[ri]) + wrowbuf[HID];
}

extern "C" void kernel_launch(void* const* d_in, const int* in_sizes, int n_in,
                              void* d_out, int out_size, void* d_ws, size_t ws_size,
                              hipStream_t stream) {
    const float* x  = (const float*)d_in[0];
    const int*  eis = (const int*)d_in[1];
    const float* W1 = (const float*)d_in[2];
    const float* b1 = (const float*)d_in[3];
    const float* W2 = (const float*)d_in[4];
    const float* b2 = (const float*)d_in[5];
    float* out = (float*)d_out;

    // ws (4B units): H0h [N*32 halves = N*16] | T [NT] | blksum [2048] |
    //   dinv [M] | q [M] | off [M] | cnt [M] | wrowbuf [64] |
    //   binned [R*E] | ssrc [R*E]   -> ~64.6 MB
    _Float16* H0h = (_Float16*)d_ws;
    int*   T      = (int*)((float*)d_ws + (size_t)N * HID / 2);
    int*   blksum = T + NT;
    float* dinv   = (float*)(blksum + 2048);
    float* q      = dinv + M;
    int*   off    = (int*)(q + M);
    int*   cnt    = off + M;
    float* wrowbuf = (float*)(cnt + M);
    int*   binned = (int*)(wrowbuf + 64);
    int*   ssrc   = binned + TOTE;

    constexpr int NBSCAN = (NT + BS - 1) / BS;   // 601

    k_gemm_h0<<<(N * 4 + BS - 1) / BS, BS, 0, stream>>>(x, W1, H0h);
    k_wrow  <<<1, 64, 0, stream>>>(W2, b2, wrowbuf);
    k_hist  <<<R * NBKr, BS, 0, stream>>>(eis, T);
    k_scanA <<<NBSCAN, BS, 0, stream>>>(T, T, blksum, NT);   // in-place ok
    k_scanB <<<1, BS, 0, stream>>>(blksum, NBSCAN);
    k_scanC <<<NBSCAN, BS, 0, stream>>>(T, blksum, NT);
    k_scat  <<<R * NBKr, BS, 0, stream>>>(eis, T, binned);
    k_sort2 <<<RB, BSPAN, 0, stream>>>(T, binned, ssrc, off, cnt, dinv);
    k_l1    <<<(M * 32 + BS - 1) / BS, BS, 0, stream>>>(off, cnt, ssrc, dinv,
                                                        (const half8*)H0h, b1, wrowbuf, q);
    k_l2    <<<(M * 32 + BS - 1) / BS, BS, 0, stream>>>(off, cnt, ssrc, dinv, q,
                                                        wrowbuf, out);
}

// Round 8
// 467.467 us; speedup vs baseline: 3.7492x; 1.0298x over previous
//
#include <hip/hip_runtime.h>

// EdgeFeatGAE: 2-layer GCN (R=4 relations share x, W1, W2), out = sum over
// embed dim -> [R, N].
// Algebra: layer2 collapses to scalar per node (wrow[j] = sum_k W2[j][k]);
// H0 = x@W1 is relation-independent; q[i] = dinv_i * g_i makes layer2 a pure
// scalar gather: out_i = dinv_i*(sum_src q[src] + q[i]) + sum(b2).
// R3: radix-partition into 512-node dst buckets (coalesced writes).
// R5: pack 16 records per wave gather instr (4 lanes x 16B fp16 row chunks),
// exact CSR via per-bucket counting sort, register accumulation. 1738->510us.
// R6/7: k_gemm_h0 vectorized (scalar-load-issue bound). 510->481us.
// R8: pipeline consolidation. Dynamic bucket cursors (fixed CAP segments +
// one global atomicAdd per block-bucket) kill k_hist + 3 scan kernels; sort
// done in-LDS and written back over binned (ssrc array + its random-window
// writes eliminated). 10 launches -> 7, ws 64.6 -> 41 MB.

constexpr int N    = 100000;
constexpr int E    = 1600000;
constexpr int R    = 4;
constexpr int FEAT = 128;
constexpr int HID  = 32;
constexpr int EMB  = 16;
constexpr int M    = R * N;
constexpr int BS   = 256;
constexpr int SH    = 9;                          // bucket = dst >> 9
constexpr int BSPAN = 1 << SH;                    // 512 nodes per bucket
constexpr int NBUCK = (N + BSPAN - 1) / BSPAN;    // 196 buckets per relation
constexpr int CH    = 8192;                       // edges per partition block
constexpr int NBKr  = (E + CH - 1) / CH;          // 196 blocks per relation
constexpr int RB    = R * NBUCK;                  // 784 buckets total
constexpr int CAP   = 8960;                       // bucket capacity (mean 8192 + 8.5 sigma)

typedef _Float16 half8 __attribute__((ext_vector_type(8)));   // 16B chunk

// ---------------- H0 = x @ W1  [N,32] -> fp16 ----------------
__global__ void k_gemm_h0(const float* __restrict__ x, const float* __restrict__ W1,
                          _Float16* __restrict__ H0h) {
    int t = blockIdx.x * blockDim.x + threadIdx.x;
    if (t >= N * 4) return;
    int i = t >> 2;            // node
    int jh = t & 3;            // j-octet: j = jh*8
    const float4* xr = (const float4*)(x + (size_t)i * FEAT);
    float acc[8];
#pragma unroll
    for (int kk = 0; kk < 8; ++kk) acc[kk] = 0.f;
#pragma unroll 4
    for (int k4 = 0; k4 < FEAT / 4; ++k4) {
        float4 xv = xr[k4];
        float xk[4] = {xv.x, xv.y, xv.z, xv.w};
        const float* wb = W1 + (k4 * 4) * HID + (jh << 3);
#pragma unroll
        for (int dk = 0; dk < 4; ++dk) {
            float4 wlo = *(const float4*)(wb + dk * HID);
            float4 whi = *(const float4*)(wb + dk * HID + 4);
            acc[0] = fmaf(xk[dk], wlo.x, acc[0]);
            acc[1] = fmaf(xk[dk], wlo.y, acc[1]);
            acc[2] = fmaf(xk[dk], wlo.z, acc[2]);
            acc[3] = fmaf(xk[dk], wlo.w, acc[3]);
            acc[4] = fmaf(xk[dk], whi.x, acc[4]);
            acc[5] = fmaf(xk[dk], whi.y, acc[5]);
            acc[6] = fmaf(xk[dk], whi.z, acc[6]);
            acc[7] = fmaf(xk[dk], whi.w, acc[7]);
        }
    }
    half8 hv;
#pragma unroll
    for (int kk = 0; kk < 8; ++kk) hv[kk] = (_Float16)acc[kk];
    ((half8*)H0h)[i * 4 + jh] = hv;    // 16B store, coalesced across lanes
}

// ---------------- wrow[j] = sum_k W2[j][k]; wrowbuf[32] = sum(b2) ----------
__global__ void k_wrow(const float* __restrict__ W2, const float* __restrict__ b2,
                       float* __restrict__ wrowbuf) {
    int j = threadIdx.x;
    if (j < HID) {
        float s = 0.f;
#pragma unroll
        for (int k = 0; k < EMB; ++k) s += W2[j * EMB + k];
        wrowbuf[j] = s;
    } else if (j == HID) {
        float s = 0.f;
#pragma unroll
        for (int k = 0; k < EMB; ++k) s += b2[k];
        wrowbuf[HID] = s;
    }
}

// ---------------- partition: LDS-staged, dynamic bucket-cursor reservation --
__global__ void k_scat2(const int* __restrict__ eis, int* __restrict__ gcur,
                        int* __restrict__ binned) {
    __shared__ int hist[NBUCK], lstart[NBUCK], cursor[NBUCK], gbase[NBUCK];
    __shared__ int sc[BS];
    __shared__ int shuf[CH];              // 32 KB
    __shared__ unsigned char bkt[CH];     // 8 KB
    int r = blockIdx.x / NBKr, k = blockIdx.x - r * NBKr;
    const int* srcp = eis + (size_t)r * 2 * E;
    const int* dstp = srcp + E;
    int e0 = k * CH, n = min(CH, E - e0);
    for (int b = threadIdx.x; b < NBUCK; b += BS) hist[b] = 0;
    __syncthreads();
    for (int i = threadIdx.x; i < n; i += BS)
        atomicAdd(&hist[dstp[e0 + i] >> SH], 1);
    __syncthreads();
    // exclusive prefix over NBUCK (<= BS) entries
    int v = (threadIdx.x < NBUCK) ? hist[threadIdx.x] : 0;
    sc[threadIdx.x] = v;
    __syncthreads();
#pragma unroll
    for (int d = 1; d < BS; d <<= 1) {
        int x = (threadIdx.x >= d) ? sc[threadIdx.x - d] : 0;
        __syncthreads();
        sc[threadIdx.x] += x;
        __syncthreads();
    }
    if (threadIdx.x < NBUCK) {
        int ex = sc[threadIdx.x] - v;
        lstart[threadIdx.x] = ex;
        cursor[threadIdx.x] = ex;
        // reserve a contiguous range in this bucket's segment (R8)
        gbase[threadIdx.x] = atomicAdd(&gcur[r * NBUCK + threadIdx.x], v);
    }
    __syncthreads();
    // local scatter into LDS (bucket-ordered)
    for (int i = threadIdx.x; i < n; i += BS) {
        int d = dstp[e0 + i];
        int b = d >> SH;
        int pos = atomicAdd(&cursor[b], 1);
        shuf[pos] = ((d & (BSPAN - 1)) << 17) | srcp[e0 + i];   // src < 2^17
        bkt[pos]  = (unsigned char)b;
    }
    __syncthreads();
    // coalesced emission into CAP-strided bucket segments
    for (int i = threadIdx.x; i < n; i += BS) {
        int b = bkt[i];
        int pos = gbase[b] + (i - lstart[b]);
        if (pos < CAP)
            binned[(size_t)(r * NBUCK + b) * CAP + pos] = shuf[i];
    }
}

// ---------------- per-bucket in-LDS counting sort (in place) + CSR + dinv ---
__global__ __launch_bounds__(BSPAN)
void k_sort3(const int* __restrict__ gcur, int* __restrict__ binned,
             int* __restrict__ off, int* __restrict__ cnt,
             float* __restrict__ dinv) {
    __shared__ int shuf[CAP];                       // 35.8 KB
    __shared__ int hist[BSPAN], sc[BSPAN], cur[BSPAN];  // 6 KB
    int gb = blockIdx.x;
    int r = gb / NBUCK, b = gb - r * NBUCK;
    int n = min(gcur[gb], CAP);
    int base = gb * CAP;
    int tid = threadIdx.x;            // 0..511
    hist[tid] = 0;
    for (int i = tid; i < n; i += BSPAN) shuf[i] = binned[base + i];  // coalesced
    __syncthreads();
    for (int i = tid; i < n; i += BSPAN)
        atomicAdd(&hist[((unsigned)shuf[i]) >> 17], 1);
    __syncthreads();
    int v = hist[tid];
    sc[tid] = v;
    __syncthreads();
#pragma unroll
    for (int d = 1; d < BSPAN; d <<= 1) {
        int x = (tid >= d) ? sc[tid - d] : 0;
        __syncthreads();
        sc[tid] += x;
        __syncthreads();
    }
    int ex = sc[tid] - v;
    cur[tid] = ex;
    int node = (b << SH) + tid;
    if (node < N) {
        int ri = r * N + node;
        off[ri] = base + ex;
        cnt[ri] = v;
        dinv[ri] = rsqrtf((float)v + 1.0f);
    }
    __syncthreads();
    // scatter src back over binned, sorted by node (reads from LDS only)
    for (int i = tid; i < n; i += BSPAN) {
        int rc = shuf[i];
        int pos = atomicAdd(&cur[((unsigned)rc) >> 17], 1);
        binned[base + pos] = rc & 0x1FFFF;
    }
}

// ---------------- layer 1: 32 lanes/node, 4 lanes/record, register acc ------
// One wave64 gather instruction carries 16 random 64B fp16 rows.
__global__ void k_l1(const int* __restrict__ off, const int* __restrict__ cnt,
                     const int* __restrict__ ssrc, const float* __restrict__ dinv,
                     const half8* __restrict__ H0h, const float* __restrict__ b1,
                     const float* __restrict__ wrowbuf, float* __restrict__ q) {
    int t = blockIdx.x * blockDim.x + threadIdx.x;
    int ri = t >> 5;
    if (ri >= M) return;
    int lane = t & 31;
    int c   = lane & 3;        // 16B chunk of the 64B row
    int sub = lane >> 2;       // record slot 0..7
    int i = ri % N;
    int rbase = ri - i;
    float di = dinv[ri];
    half8 hs = H0h[i * 4 + c];                 // self row chunk
    float acc[8];
#pragma unroll
    for (int kk = 0; kk < 8; ++kk) acc[kk] = 0.f;
    int base = off[ri], n = cnt[ri];
    for (int k0 = 0; k0 < n; k0 += 32) {
        int sb_ = (k0 + lane < n) ? ssrc[base + k0 + lane] : 0;   // coalesced
        int m = n - k0;                         // records left in this window
        for (int bq = 0; bq < 4 && bq * 8 < m; ++bq) {
            int slot = bq * 8 + sub;
            int sj = __shfl(sb_, slot, 32);
            float dv = (slot < m) ? dinv[rbase + sj] : 0.f;
            half8 h = H0h[sj * 4 + c];          // 16B/lane -> 16 rows per wave instr
#pragma unroll
            for (int kk = 0; kk < 8; ++kk)
                acc[kk] = fmaf(dv, (float)h[kk], acc[kk]);
        }
    }
    // reduce over record slots (lanes c, c+4, ..., c+28 hold same chunk)
#pragma unroll
    for (int o = 4; o <= 16; o <<= 1)
#pragma unroll
        for (int kk = 0; kk < 8; ++kk) acc[kk] += __shfl_xor(acc[kk], o, 32);
    // epilogue: h1 = relu(di*acc + di^2*H0self + b1); p = h1 . wrow
    float di2 = di * di;
    float p = 0.f;
#pragma unroll
    for (int kk = 0; kk < 8; ++kk) {
        int j = c * 8 + kk;
        float h1 = fmaf(di, acc[kk], fmaf(di2, (float)hs[kk], b1[j]));
        h1 = fmaxf(h1, 0.f);
        p = fmaf(h1, wrowbuf[j], p);
    }
    p += __shfl_xor(p, 1, 32);
    p += __shfl_xor(p, 2, 32);
    if (lane == 0) q[ri] = di * p;              // q = dinv * g
}

// ---------------- layer 2: per-lane scalar gathers of q + finalize ----------
__global__ void k_l2(const int* __restrict__ off, const int* __restrict__ cnt,
                     const int* __restrict__ ssrc, const float* __restrict__ dinv,
                     const float* __restrict__ q, const float* __restrict__ wrowbuf,
                     float* __restrict__ out) {
    int t = blockIdx.x * blockDim.x + threadIdx.x;
    int ri = t >> 5;
    if (ri >= M) return;
    int lane = t & 31;
    int i = ri % N;
    int rbase = ri - i;
    int base = off[ri], n = cnt[ri];
    float val = 0.f;
    for (int idx = lane; idx < n; idx += 32) {
        int s = ssrc[base + idx];               // coalesced
        val += q[rbase + s];                    // 4B gather, 1.6MB L2-resident
    }
#pragma unroll
    for (int o = 16; o > 0; o >>= 1) val += __shfl_xor(val, o, 32);
    if (lane == 0)
        out[ri] = dinv[ri] * (val + q[ri]) + wrowbuf[HID];
}

extern "C" void kernel_launch(void* const* d_in, const int* in_sizes, int n_in,
                              void* d_out, int out_size, void* d_ws, size_t ws_size,
                              hipStream_t stream) {
    const float* x  = (const float*)d_in[0];
    const int*  eis = (const int*)d_in[1];
    const float* W1 = (const float*)d_in[2];
    const float* b1 = (const float*)d_in[3];
    const float* W2 = (const float*)d_in[4];
    const float* b2 = (const float*)d_in[5];
    float* out = (float*)d_out;

    // ws (4B units): H0h [N*16] | dinv [M] | q [M] | off [M] | cnt [M] |
    //   wrowbuf [64] | gcur [RB] | binned [RB*CAP]   -> ~41 MB
    _Float16* H0h = (_Float16*)d_ws;
    float* dinv   = (float*)d_ws + (size_t)N * HID / 2;
    float* q      = dinv + M;
    int*   off    = (int*)(q + M);
    int*   cnt    = off + M;
    float* wrowbuf = (float*)(cnt + M);
    int*   gcur   = (int*)(wrowbuf + 64);
    int*   binned = gcur + RB;

    k_gemm_h0<<<(N * 4 + BS - 1) / BS, BS, 0, stream>>>(x, W1, H0h);
    k_wrow  <<<1, 64, 0, stream>>>(W2, b2, wrowbuf);
    hipMemsetAsync(gcur, 0, (size_t)RB * sizeof(int), stream);
    k_scat2 <<<R * NBKr, BS, 0, stream>>>(eis, gcur, binned);
    k_sort3 <<<RB, BSPAN, 0, stream>>>(gcur, binned, off, cnt, dinv);
    k_l1    <<<(M * 32 + BS - 1) / BS, BS, 0, stream>>>(off, cnt, binned, dinv,
                                                        (const half8*)H0h, b1, wrowbuf, q);
    k_l2    <<<(M * 32 + BS - 1) / BS, BS, 0, stream>>>(off, cnt, binned, dinv, q,
                                                        wrowbuf, out);
}

// Round 9
// 436.197 us; speedup vs baseline: 4.0180x; 1.0717x over previous
//
#include <hip/hip_runtime.h>

// EdgeFeatGAE: 2-layer GCN (R=4 relations share x, W1, W2), out = sum over
// embed dim -> [R, N].
// Algebra: layer2 collapses to scalar per node (wrow[j] = sum_k W2[j][k]);
// H0 = x@W1 is relation-independent; q[i] = dinv_i * g_i makes layer2 a pure
// scalar gather: out_i = dinv_i*(sum_src q[src] + q[i]) + sum(b2).
// R3: radix-partition into 512-node dst buckets (coalesced writes).
// R5: pack 16 records per wave gather instr (4 lanes x 16B fp16 row chunks),
// exact CSR via per-bucket counting sort, register accumulation. 1738->510us.
// R6/7: k_gemm_h0 vectorized (scalar-load-issue bound). 510->481us.
// R8: dynamic bucket cursors kill hist+scan kernels; in-LDS sort. 481->467us.
// R9: k_scat2 was occupancy-starved (19% occ, 45.5KB LDS -> 3 blocks/CU,
// VALU 4.7%, latency-bound). CH 8192->4096: 24.2KB LDS -> 6 blocks/CU,
// 2x grid -> 4x resident waves.

constexpr int N    = 100000;
constexpr int E    = 1600000;
constexpr int R    = 4;
constexpr int FEAT = 128;
constexpr int HID  = 32;
constexpr int EMB  = 16;
constexpr int M    = R * N;
constexpr int BS   = 256;
constexpr int SH    = 9;                          // bucket = dst >> 9
constexpr int BSPAN = 1 << SH;                    // 512 nodes per bucket
constexpr int NBUCK = (N + BSPAN - 1) / BSPAN;    // 196 buckets per relation
constexpr int CH    = 4096;                       // edges per partition block (R9)
constexpr int NBKr  = (E + CH - 1) / CH;          // 391 blocks per relation
constexpr int RB    = R * NBUCK;                  // 784 buckets total
constexpr int CAP   = 8960;                       // bucket capacity (mean 8192 + 8.5 sigma)

typedef _Float16 half8 __attribute__((ext_vector_type(8)));   // 16B chunk

// ---------------- H0 = x @ W1  [N,32] -> fp16 ----------------
__global__ void k_gemm_h0(const float* __restrict__ x, const float* __restrict__ W1,
                          _Float16* __restrict__ H0h) {
    int t = blockIdx.x * blockDim.x + threadIdx.x;
    if (t >= N * 4) return;
    int i = t >> 2;            // node
    int jh = t & 3;            // j-octet: j = jh*8
    const float4* xr = (const float4*)(x + (size_t)i * FEAT);
    float acc[8];
#pragma unroll
    for (int kk = 0; kk < 8; ++kk) acc[kk] = 0.f;
#pragma unroll 4
    for (int k4 = 0; k4 < FEAT / 4; ++k4) {
        float4 xv = xr[k4];
        float xk[4] = {xv.x, xv.y, xv.z, xv.w};
        const float* wb = W1 + (k4 * 4) * HID + (jh << 3);
#pragma unroll
        for (int dk = 0; dk < 4; ++dk) {
            float4 wlo = *(const float4*)(wb + dk * HID);
            float4 whi = *(const float4*)(wb + dk * HID + 4);
            acc[0] = fmaf(xk[dk], wlo.x, acc[0]);
            acc[1] = fmaf(xk[dk], wlo.y, acc[1]);
            acc[2] = fmaf(xk[dk], wlo.z, acc[2]);
            acc[3] = fmaf(xk[dk], wlo.w, acc[3]);
            acc[4] = fmaf(xk[dk], whi.x, acc[4]);
            acc[5] = fmaf(xk[dk], whi.y, acc[5]);
            acc[6] = fmaf(xk[dk], whi.z, acc[6]);
            acc[7] = fmaf(xk[dk], whi.w, acc[7]);
        }
    }
    half8 hv;
#pragma unroll
    for (int kk = 0; kk < 8; ++kk) hv[kk] = (_Float16)acc[kk];
    ((half8*)H0h)[i * 4 + jh] = hv;    // 16B store, coalesced across lanes
}

// ---------------- wrow[j] = sum_k W2[j][k]; wrowbuf[32] = sum(b2) ----------
__global__ void k_wrow(const float* __restrict__ W2, const float* __restrict__ b2,
                       float* __restrict__ wrowbuf) {
    int j = threadIdx.x;
    if (j < HID) {
        float s = 0.f;
#pragma unroll
        for (int k = 0; k < EMB; ++k) s += W2[j * EMB + k];
        wrowbuf[j] = s;
    } else if (j == HID) {
        float s = 0.f;
#pragma unroll
        for (int k = 0; k < EMB; ++k) s += b2[k];
        wrowbuf[HID] = s;
    }
}

// ---------------- partition: LDS-staged, dynamic bucket-cursor reservation --
__global__ void k_scat2(const int* __restrict__ eis, int* __restrict__ gcur,
                        int* __restrict__ binned) {
    __shared__ int hist[NBUCK], lstart[NBUCK], cursor[NBUCK], gbase[NBUCK];
    __shared__ int sc[BS];
    __shared__ int shuf[CH];              // 16 KB (R9)
    __shared__ unsigned char bkt[CH];     // 4 KB
    int r = blockIdx.x / NBKr, k = blockIdx.x - r * NBKr;
    const int* srcp = eis + (size_t)r * 2 * E;
    const int* dstp = srcp + E;
    int e0 = k * CH, n = min(CH, E - e0);
    for (int b = threadIdx.x; b < NBUCK; b += BS) hist[b] = 0;
    __syncthreads();
    for (int i = threadIdx.x; i < n; i += BS)
        atomicAdd(&hist[dstp[e0 + i] >> SH], 1);
    __syncthreads();
    // exclusive prefix over NBUCK (<= BS) entries
    int v = (threadIdx.x < NBUCK) ? hist[threadIdx.x] : 0;
    sc[threadIdx.x] = v;
    __syncthreads();
#pragma unroll
    for (int d = 1; d < BS; d <<= 1) {
        int x = (threadIdx.x >= d) ? sc[threadIdx.x - d] : 0;
        __syncthreads();
        sc[threadIdx.x] += x;
        __syncthreads();
    }
    if (threadIdx.x < NBUCK) {
        int ex = sc[threadIdx.x] - v;
        lstart[threadIdx.x] = ex;
        cursor[threadIdx.x] = ex;
        // reserve a contiguous range in this bucket's segment
        gbase[threadIdx.x] = atomicAdd(&gcur[r * NBUCK + threadIdx.x], v);
    }
    __syncthreads();
    // local scatter into LDS (bucket-ordered)
    for (int i = threadIdx.x; i < n; i += BS) {
        int d = dstp[e0 + i];
        int b = d >> SH;
        int pos = atomicAdd(&cursor[b], 1);
        shuf[pos] = ((d & (BSPAN - 1)) << 17) | srcp[e0 + i];   // src < 2^17
        bkt[pos]  = (unsigned char)b;
    }
    __syncthreads();
    // coalesced emission into CAP-strided bucket segments
    for (int i = threadIdx.x; i < n; i += BS) {
        int b = bkt[i];
        int pos = gbase[b] + (i - lstart[b]);
        if (pos < CAP)
            binned[(size_t)(r * NBUCK + b) * CAP + pos] = shuf[i];
    }
}

// ---------------- per-bucket in-LDS counting sort (in place) + CSR + dinv ---
__global__ __launch_bounds__(BSPAN)
void k_sort3(const int* __restrict__ gcur, int* __restrict__ binned,
             int* __restrict__ off, int* __restrict__ cnt,
             float* __restrict__ dinv) {
    __shared__ int shuf[CAP];                       // 35.8 KB
    __shared__ int hist[BSPAN], sc[BSPAN], cur[BSPAN];  // 6 KB
    int gb = blockIdx.x;
    int r = gb / NBUCK, b = gb - r * NBUCK;
    int n = min(gcur[gb], CAP);
    int base = gb * CAP;
    int tid = threadIdx.x;            // 0..511
    hist[tid] = 0;
    for (int i = tid; i < n; i += BSPAN) shuf[i] = binned[base + i];  // coalesced
    __syncthreads();
    for (int i = tid; i < n; i += BSPAN)
        atomicAdd(&hist[((unsigned)shuf[i]) >> 17], 1);
    __syncthreads();
    int v = hist[tid];
    sc[tid] = v;
    __syncthreads();
#pragma unroll
    for (int d = 1; d < BSPAN; d <<= 1) {
        int x = (tid >= d) ? sc[tid - d] : 0;
        __syncthreads();
        sc[tid] += x;
        __syncthreads();
    }
    int ex = sc[tid] - v;
    cur[tid] = ex;
    int node = (b << SH) + tid;
    if (node < N) {
        int ri = r * N + node;
        off[ri] = base + ex;
        cnt[ri] = v;
        dinv[ri] = rsqrtf((float)v + 1.0f);
    }
    __syncthreads();
    // scatter src back over binned, sorted by node (reads from LDS only)
    for (int i = tid; i < n; i += BSPAN) {
        int rc = shuf[i];
        int pos = atomicAdd(&cur[((unsigned)rc) >> 17], 1);
        binned[base + pos] = rc & 0x1FFFF;
    }
}

// ---------------- layer 1: 32 lanes/node, 4 lanes/record, register acc ------
// One wave64 gather instruction carries 16 random 64B fp16 rows.
__global__ void k_l1(const int* __restrict__ off, const int* __restrict__ cnt,
                     const int* __restrict__ ssrc, const float* __restrict__ dinv,
                     const half8* __restrict__ H0h, const float* __restrict__ b1,
                     const float* __restrict__ wrowbuf, float* __restrict__ q) {
    int t = blockIdx.x * blockDim.x + threadIdx.x;
    int ri = t >> 5;
    if (ri >= M) return;
    int lane = t & 31;
    int c   = lane & 3;        // 16B chunk of the 64B row
    int sub = lane >> 2;       // record slot 0..7
    int i = ri % N;
    int rbase = ri - i;
    float di = dinv[ri];
    half8 hs = H0h[i * 4 + c];                 // self row chunk
    float acc[8];
#pragma unroll
    for (int kk = 0; kk < 8; ++kk) acc[kk] = 0.f;
    int base = off[ri], n = cnt[ri];
    for (int k0 = 0; k0 < n; k0 += 32) {
        int sb_ = (k0 + lane < n) ? ssrc[base + k0 + lane] : 0;   // coalesced
        int m = n - k0;                         // records left in this window
        for (int bq = 0; bq < 4 && bq * 8 < m; ++bq) {
            int slot = bq * 8 + sub;
            int sj = __shfl(sb_, slot, 32);
            float dv = (slot < m) ? dinv[rbase + sj] : 0.f;
            half8 h = H0h[sj * 4 + c];          // 16B/lane -> 16 rows per wave instr
#pragma unroll
            for (int kk = 0; kk < 8; ++kk)
                acc[kk] = fmaf(dv, (float)h[kk], acc[kk]);
        }
    }
    // reduce over record slots (lanes c, c+4, ..., c+28 hold same chunk)
#pragma unroll
    for (int o = 4; o <= 16; o <<= 1)
#pragma unroll
        for (int kk = 0; kk < 8; ++kk) acc[kk] += __shfl_xor(acc[kk], o, 32);
    // epilogue: h1 = relu(di*acc + di^2*H0self + b1); p = h1 . wrow
    float di2 = di * di;
    float p = 0.f;
#pragma unroll
    for (int kk = 0; kk < 8; ++kk) {
        int j = c * 8 + kk;
        float h1 = fmaf(di, acc[kk], fmaf(di2, (float)hs[kk], b1[j]));
        h1 = fmaxf(h1, 0.f);
        p = fmaf(h1, wrowbuf[j], p);
    }
    p += __shfl_xor(p, 1, 32);
    p += __shfl_xor(p, 2, 32);
    if (lane == 0) q[ri] = di * p;              // q = dinv * g
}

// ---------------- layer 2: per-lane scalar gathers of q + finalize ----------
__global__ void k_l2(const int* __restrict__ off, const int* __restrict__ cnt,
                     const int* __restrict__ ssrc, const float* __restrict__ dinv,
                     const float* __restrict__ q, const float* __restrict__ wrowbuf,
                     float* __restrict__ out) {
    int t = blockIdx.x * blockDim.x + threadIdx.x;
    int ri = t >> 5;
    if (ri >= M) return;
    int lane = t & 31;
    int i = ri % N;
    int rbase = ri - i;
    int base = off[ri], n = cnt[ri];
    float val = 0.f;
    for (int idx = lane; idx < n; idx += 32) {
        int s = ssrc[base + idx];               // coalesced
        val += q[rbase + s];                    // 4B gather, 1.6MB L2-resident
    }
#pragma unroll
    for (int o = 16; o > 0; o >>= 1) val += __shfl_xor(val, o, 32);
    if (lane == 0)
        out[ri] = dinv[ri] * (val + q[ri]) + wrowbuf[HID];
}

extern "C" void kernel_launch(void* const* d_in, const int* in_sizes, int n_in,
                              void* d_out, int out_size, void* d_ws, size_t ws_size,
                              hipStream_t stream) {
    const float* x  = (const float*)d_in[0];
    const int*  eis = (const int*)d_in[1];
    const float* W1 = (const float*)d_in[2];
    const float* b1 = (const float*)d_in[3];
    const float* W2 = (const float*)d_in[4];
    const float* b2 = (const float*)d_in[5];
    float* out = (float*)d_out;

    // ws (4B units): H0h [N*16] | dinv [M] | q [M] | off [M] | cnt [M] |
    //   wrowbuf [64] | gcur [RB] | binned [RB*CAP]   -> ~41 MB
    _Float16* H0h = (_Float16*)d_ws;
    float* dinv   = (float*)d_ws + (size_t)N * HID / 2;
    float* q      = dinv + M;
    int*   off    = (int*)(q + M);
    int*   cnt    = off + M;
    float* wrowbuf = (float*)(cnt + M);
    int*   gcur   = (int*)(wrowbuf + 64);
    int*   binned = gcur + RB;

    k_gemm_h0<<<(N * 4 + BS - 1) / BS, BS, 0, stream>>>(x, W1, H0h);
    k_wrow  <<<1, 64, 0, stream>>>(W2, b2, wrowbuf);
    hipMemsetAsync(gcur, 0, (size_t)RB * sizeof(int), stream);
    k_scat2 <<<R * NBKr, BS, 0, stream>>>(eis, gcur, binned);
    k_sort3 <<<RB, BSPAN, 0, stream>>>(gcur, binned, off, cnt, dinv);
    k_l1    <<<(M * 32 + BS - 1) / BS, BS, 0, stream>>>(off, cnt, binned, dinv,
                                                        (const half8*)H0h, b1, wrowbuf, q);
    k_l2    <<<(M * 32 + BS - 1) / BS, BS, 0, stream>>>(off, cnt, binned, dinv, q,
                                                        wrowbuf, out);
}